// Round 21
// baseline (202.188 us; speedup 1.0000x reference)
//
#include <hip/hip_runtime.h>
#include <math.h>

#define CC 96
#define BB 512
#define TT 512

// ---------------------------------------------------------------------------
// Kernel 0: column max of transitions and E[i][j] = exp(T[i][j]-maxT[j])
// ---------------------------------------------------------------------------
__global__ __launch_bounds__(128) void crf_prep(const float* __restrict__ trans,
                                                float* __restrict__ E,
                                                float* __restrict__ maxT) {
    int j = threadIdx.x;
    if (j < CC) {
        float m = -INFINITY;
        for (int i = 0; i < CC; ++i) m = fmaxf(m, trans[i * CC + j]);
        maxT[j] = m;
        for (int i = 0; i < CC; ++i) E[i * CC + j] = __expf(trans[i * CC + j] - m);
    }
}

// ---------------------------------------------------------------------------
// Kernel 0b: pack mask rows into bit-words (no per-step SMEM loads).
// ---------------------------------------------------------------------------
__global__ __launch_bounds__(64) void pack_mask(const int* __restrict__ mask,
                                                unsigned* __restrict__ mbits) {
    const int b = blockIdx.x;
    const int w = threadIdx.x;
    if (w < 16) {
        unsigned bits = 0u;
        for (int k = 0; k < 32; ++k)
            bits |= (mask[b * TT + w * 32 + k] ? 1u : 0u) << k;
        mbits[b * 16 + w] = bits;
    }
}

// ---------------------------------------------------------------------------
// Kernel 1: BIDIRECTIONAL halves, 2-wave i-split (r20) + DS-instruction DIET.
// r20 diagnosis: per-CU DS pipe is ISSUE-saturated — 2 waves x 28 DS instrs
// x 4 chains/CU ~ 1330cy/step ~ measured 1560. (r17/r18 "bank 0/24/16/8"
// claim was a units error: 96 floats = 384B -> all 4 addrs bank 0.)
// Diet, math-identical: (1) p-half broadcast as 12x ds_read_b128 (uniform
// addr, pb 16B-aligned) instead of 24x b64; (2) pex layout [par][pair][4]:
// wave w writes slots 2w..2w+1, readback is ONE b128 (16B lane stride,
// bank-sequential) instead of two b64 reads. q = (x+z, y+w) == old o0+o1.
// DS/wave/step ~28 -> ~16. Everything else identical to r20.
// ---------------------------------------------------------------------------
#define PKFMA_LO(A_, S_, E_) \
    asm("v_pk_fma_f32 %0, %1, %2, %0 op_sel:[0,0,0] op_sel_hi:[0,1,1]" \
        : "+v"(A_) : "v"(S_), "v"(E_))
#define PKFMA_HI(A_, S_, E_) \
    asm("v_pk_fma_f32 %0, %1, %2, %0 op_sel:[1,0,0] op_sel_hi:[1,1,1]" \
        : "+v"(A_) : "v"(S_), "v"(E_))

// shared matvec body: 12 b128 broadcast reads of own p/u-half + 48 pk_fma
#define HALF_MATVEC(SRC_, ER_)                                                \
    float2 a0={0.f,0.f}, a1={0.f,0.f}, a2={0.f,0.f}, a3={0.f,0.f};            \
    _Pragma("unroll")                                                         \
    for (int k_ = 0; k_ < 48; k_ += 8) {                                      \
        const float4 v0_ = *(const float4*)&SRC_[k_];                         \
        const float4 v1_ = *(const float4*)&SRC_[k_ + 4];                     \
        const float2 pA_ = make_float2(v0_.x, v0_.y);                         \
        const float2 pB_ = make_float2(v0_.z, v0_.w);                         \
        const float2 pC_ = make_float2(v1_.x, v1_.y);                         \
        const float2 pD_ = make_float2(v1_.z, v1_.w);                         \
        PKFMA_LO(a0, pA_, ER_[k_]);                                           \
        PKFMA_HI(a1, pA_, ER_[k_ + 1]);                                       \
        PKFMA_LO(a2, pB_, ER_[k_ + 2]);                                       \
        PKFMA_HI(a3, pB_, ER_[k_ + 3]);                                       \
        PKFMA_LO(a0, pC_, ER_[k_ + 4]);                                       \
        PKFMA_HI(a1, pC_, ER_[k_ + 5]);                                       \
        PKFMA_LO(a2, pD_, ER_[k_ + 6]);                                       \
        PKFMA_HI(a3, pD_, ER_[k_ + 7]);                                       \
    }                                                                         \
    float2 mine_;                                                             \
    mine_.x = (a0.x + a1.x) + (a2.x + a3.x);                                  \
    mine_.y = (a0.y + a1.y) + (a2.y + a3.y);

// forward step: consume em_t, half-matvec, one-b128 exchange, scale-after
#define FSTEP(PF_, K_, BIT_, REN_) do {                                       \
    const int sl_ = (K_) & 3;                                                 \
    const int pr_ = (K_) & 1;                                                 \
    const float2 ce_ = es[sl_];                                               \
    es[sl_] = *(const float2*)(PF_);                                          \
    const float scx_ = __expf(mTx + ce_.x);                                   \
    const float scy_ = __expf(mTy + ce_.y);                                   \
    const float* psrc_ = pb[w][pr_];                                          \
    HALF_MATVEC(psrc_, ep2)                                                   \
    if (act) *(float2*)&pex[pr_][l][2 * w] = mine_;                           \
    asm volatile("s_waitcnt lgkmcnt(0)" ::: "memory");                        \
    __builtin_amdgcn_s_barrier();                                             \
    const float4 ex_ = *(const float4*)&pex[pr_][lc][0];                      \
    const float qx_ = ex_.x + ex_.z;                                          \
    const float qy_ = ex_.y + ex_.w;                                          \
    if (BIT_) { px = qx_ * scx_; py = qy_ * scy_; }                           \
    if (REN_) {                                                               \
        float r_ = px + py;                                                   \
        _Pragma("unroll")                                                     \
        for (int o_ = 32; o_; o_ >>= 1) r_ += __shfl_xor(r_, o_);             \
        const float inv_ = 1.0f / r_;                                         \
        px *= inv_; py *= inv_;                                               \
        S += (double)__logf(r_);                                              \
    }                                                                         \
    if (l >= wlo && l < whi)                                                  \
        *(float2*)&pb[w][pr_ ^ 1][2 * l - 48 * w] = make_float2(px, py);      \
} while (0)

// backward step: half-matvec E.u with previously published u = sc (.) c;
// masked update; publish next u scaled-before. Same sync structure.
#define BSTEP(PF_, SL_, PR_, BIT_, REN_) do {                                 \
    const float2 ce_ = es[SL_];                                               \
    es[SL_] = *(const float2*)(PF_);                                          \
    const float* usrc_ = pb[w][PR_];                                          \
    HALF_MATVEC(usrc_, eb2)                                                   \
    if (act) *(float2*)&pex[PR_][l][2 * w] = mine_;                           \
    asm volatile("s_waitcnt lgkmcnt(0)" ::: "memory");                        \
    __builtin_amdgcn_s_barrier();                                             \
    const float4 ex_ = *(const float4*)&pex[PR_][lc][0];                      \
    const float qx_ = ex_.x + ex_.z;                                          \
    const float qy_ = ex_.y + ex_.w;                                          \
    if (act && (BIT_)) { cx = qx_; cy = qy_; }                                \
    if (REN_) {                                                               \
        float r_ = cx + cy;                                                   \
        _Pragma("unroll")                                                     \
        for (int o_ = 32; o_; o_ >>= 1) r_ += __shfl_xor(r_, o_);             \
        const float inv_ = 1.0f / r_;                                         \
        cx *= inv_; cy *= inv_;                                               \
        S += (double)__logf(r_);                                              \
    }                                                                         \
    if (l >= wlo && l < whi)                                                  \
        *(float2*)&pb[w][(PR_) ^ 1][2 * l - 48 * w] =                         \
            make_float2(__expf(mTx + ce_.x) * cx, __expf(mTy + ce_.y) * cy);  \
} while (0)

__global__ __launch_bounds__(128, 1)
void crf_half(const float* __restrict__ emissions,
              const unsigned* __restrict__ mbits,
              const float* __restrict__ start_t,
              const float* __restrict__ end_t,
              const float* __restrict__ E,
              const float* __restrict__ maxT,
              float* __restrict__ pmid, float* __restrict__ cmid,
              double* __restrict__ Sf, double* __restrict__ Sb) {
    const int dir = blockIdx.x >> 9;      // 0 = forward half, 1 = backward half
    const int b = blockIdx.x & 511;
    const int w = threadIdx.x >> 6;       // wave 0/1: owns i-half [48w, 48w+48)
    const int l = threadIdx.x & 63;
    const bool act = (l < 48);
    const int lc = act ? l : 47;
    const int s0 = 2 * lc;                // owned state pair
    const int wlo = 24 * w, whi = 24 * w + 24;

    __shared__ __align__(16) float pb[2][2][48];    // self-published halves
    __shared__ __align__(16) float pex[2][48][4];   // merged exchange [par][pair][slot]

    const float* ep = emissions + (size_t)b * TT * CC + s0;
    const float mTx = act ? maxT[s0]     : -INFINITY;
    const float mTy = act ? maxT[s0 + 1] : -INFINITY;
    double S = 0.0;
    float2 es[4];

    if (dir == 0) {
        // ---------------- forward half: t = 1..255 ----------------
        float2 ep2[48];                    // E[i][s0], E[i][s0+1], i in wave half
#pragma unroll
        for (int k = 0; k < 48; ++k)
            ep2[k] = *(const float2*)(E + (size_t)(48 * w + k) * CC + s0);

        float px = 0.f, py = 0.f;
        {
            const float2 e0 = *(const float2*)ep;
            if (act) {
                px = __expf(start_t[s0]     + e0.x);
                py = __expf(start_t[s0 + 1] + e0.y);
            }
        }
        if (l >= wlo && l < whi)
            *(float2*)&pb[w][1][2 * l - 48 * w] = make_float2(px, py);

#pragma unroll
        for (int s = 1; s <= 4; ++s) es[s & 3] = *(const float2*)(ep + (size_t)s * CC);
        const float* pf = ep + (size_t)5 * CC;

        const unsigned wb0 = mbits[b * 16];
#pragma unroll
        for (int k = 1; k < 8; ++k) {
            FSTEP(pf, k, (wb0 >> k) & 1u, 0);
            pf += CC;
        }
        unsigned swc = wb0 >> 8;
        for (int sb = 1; sb < 32; ++sb) {
            const int sbn = sb + 1;
            const unsigned swn = mbits[b * 16 + (sbn >> 2)] >> ((sbn & 3) * 8);
#pragma unroll
            for (int k = 0; k < 8; ++k) {
                FSTEP(pf, k, (swc >> k) & 1u, k == 0);
                pf += CC;
            }
            swc = swn;
        }
        // state now = p_255 (renormalized), S = log-scale
        if (w == 0 && act) *(float2*)&pmid[(size_t)b * CC + s0] = make_float2(px, py);
        if (w == 0 && l == 0) Sf[b] = S;
    } else {
        // ---------------- backward half: t = 511..256 ----------------
        float2 eb2[48];                    // E[s0][j], E[s0+1][j], j in wave half
#pragma unroll
        for (int k = 0; k < 48; ++k)
            eb2[k] = make_float2(E[(size_t)s0 * CC + 48 * w + k],
                                 E[(size_t)(s0 + 1) * CC + 48 * w + k]);

        float cx = act ? __expf(end_t[s0])     : 0.f;
        float cy = act ? __expf(end_t[s0 + 1]) : 0.f;
        {   // initial publish: u_511 = sc_511 (.) c_511, into parity 0
            const float2 e511 = *(const float2*)(ep + (size_t)511 * CC);
            if (l >= wlo && l < whi)
                *(float2*)&pb[w][0][2 * l - 48 * w] =
                    make_float2(__expf(mTx + e511.x) * cx, __expf(mTy + e511.y) * cy);
        }
        // prefetch em stream m = t-1 descending: m = 510..507
#pragma unroll
        for (int s = 0; s < 4; ++s)
            es[(510 - s) & 3] = *(const float2*)(ep + (size_t)(510 - s) * CC);
        const float* pf = ep + (size_t)506 * CC;

        unsigned wv = mbits[b * 16 + 15] >> 24;          // bits t=504..511
        for (int grp = 63; grp >= 32; --grp) {
            const int gn = grp - 1;
            const unsigned wn = mbits[b * 16 + (gn >> 2)] >> ((gn & 3) * 8);
#pragma unroll
            for (int k = 0; k < 8; ++k) {                // t = 8*grp + 7 - k
                BSTEP(pf, (6 - k) & 3, k & 1, (wv >> (7 - k)) & 1u, k == 7);
                pf -= CC;
            }
            wv = wn;
        }
        // state now = c_255 (renormalized), S = log-scale
        if (w == 0 && act) *(float2*)&cmid[(size_t)b * CC + s0] = make_float2(cx, cy);
        if (w == 0 && l == 0) Sb[b] = S;
    }
}

// ---------------------------------------------------------------------------
// Kernel 1b: combine halves — log_den[b] = Sf + Sb + log(sum_j p[j]*c[j])
// ---------------------------------------------------------------------------
__global__ __launch_bounds__(64) void crf_combine(const float* __restrict__ pmid,
                                                  const float* __restrict__ cmid,
                                                  const double* __restrict__ Sf,
                                                  const double* __restrict__ Sb,
                                                  float* __restrict__ log_den) {
    const int b = blockIdx.x;
    const int l = threadIdx.x;
    float v = 0.f;
    if (l < 48) {
        const float2 p2 = *(const float2*)&pmid[(size_t)b * CC + 2 * l];
        const float2 c2 = *(const float2*)&cmid[(size_t)b * CC + 2 * l];
        v = p2.x * c2.x + p2.y * c2.y;
    }
#pragma unroll
    for (int off = 32; off; off >>= 1) v += __shfl_xor(v, off);
    if (l == 0) log_den[b] = (float)(Sf[b] + Sb[b] + (double)__logf(v));
}

// ---------------------------------------------------------------------------
// Kernel 2: joint likelihood (numerator) — one block per batch.
// ---------------------------------------------------------------------------
__global__ __launch_bounds__(256) void crf_joint(const float* __restrict__ emissions,
                                                 const int* __restrict__ tags,
                                                 const int* __restrict__ mask,
                                                 const float* __restrict__ trans,
                                                 const float* __restrict__ start_t,
                                                 const float* __restrict__ end_t,
                                                 float* __restrict__ log_num) {
    const int b = blockIdx.x;
    const int tid = threadIdx.x;
    float s = 0.f;
    int mcount = 0;
    for (int t = tid; t < TT; t += 256) {
        int tg = tags[b * TT + t];
        float em = emissions[((size_t)b * TT + t) * CC + tg];
        int mk = mask[b * TT + t];
        mcount += mk;
        if (t == 0) {
            s += start_t[tg] + em;  // t=0 term unmasked in reference
        } else {
            int tp = tags[b * TT + t - 1];
            s += mk ? (trans[tp * CC + tg] + em) : 0.f;
        }
    }
    __shared__ float sred[4];
    __shared__ int mred[4];
#pragma unroll
    for (int off = 32; off; off >>= 1) {
        s += __shfl_xor(s, off);
        mcount += __shfl_xor(mcount, off);
    }
    if ((tid & 63) == 0) { sred[tid >> 6] = s; mred[tid >> 6] = mcount; }
    __syncthreads();
    if (tid == 0) {
        float tot = (sred[0] + sred[1]) + (sred[2] + sred[3]);
        int mt = (mred[0] + mred[1]) + (mred[2] + mred[3]);
        int last_tag = tags[b * TT + (mt - 1)];
        log_num[b] = tot + end_t[last_tag];
    }
}

// ---------------------------------------------------------------------------
// Kernel 3: final mean(log_den - log_num)
// ---------------------------------------------------------------------------
__global__ __launch_bounds__(512) void crf_final(const float* __restrict__ log_den,
                                                 const float* __restrict__ log_num,
                                                 float* __restrict__ out) {
    const int tid = threadIdx.x;
    float d = log_den[tid] - log_num[tid];
#pragma unroll
    for (int off = 32; off; off >>= 1) d += __shfl_xor(d, off);
    __shared__ float sred[8];
    if ((tid & 63) == 0) sred[tid >> 6] = d;
    __syncthreads();
    if (tid == 0) {
        float tot = 0.f;
        for (int w = 0; w < 8; ++w) tot += sred[w];
        out[0] = tot / (float)BB;
    }
}

extern "C" void kernel_launch(void* const* d_in, const int* in_sizes, int n_in,
                              void* d_out, int out_size, void* d_ws, size_t ws_size,
                              hipStream_t stream) {
    const float* emissions = (const float*)d_in[0];
    const int*   tags      = (const int*)d_in[1];
    const int*   mask      = (const int*)d_in[2];
    const float* trans     = (const float*)d_in[3];
    const float* start_t   = (const float*)d_in[4];
    const float* end_t     = (const float*)d_in[5];
    float* out = (float*)d_out;

    float*    ws      = (float*)d_ws;
    float*    E       = ws;                         // 9216 f
    float*    maxT    = ws + 9216;                  // 96 f
    float*    log_den = ws + 9312;                  // 512 f
    float*    log_num = ws + 9824;                  // 512 f
    unsigned* mbits   = (unsigned*)(ws + 10336);    // 8192 u32
    float*    pmid    = ws + 18528;                 // 512*96 f
    float*    cmid    = ws + 67680;                 // 512*96 f
    double*   Sf      = (double*)(ws + 116832);     // 512 d (8B aligned)
    double*   Sb      = (double*)(ws + 117856);     // 512 d

    crf_prep<<<1, 128, 0, stream>>>(trans, E, maxT);
    pack_mask<<<BB, 64, 0, stream>>>(mask, mbits);
    crf_half<<<2 * BB, 128, 0, stream>>>(emissions, mbits, start_t, end_t, E, maxT,
                                         pmid, cmid, Sf, Sb);
    crf_combine<<<BB, 64, 0, stream>>>(pmid, cmid, Sf, Sb, log_den);
    crf_joint<<<BB, 256, 0, stream>>>(emissions, tags, mask, trans, start_t, end_t, log_num);
    crf_final<<<1, 512, 0, stream>>>(log_den, log_num, out);
}